// Round 2
// baseline (684.558 us; speedup 1.0000x reference)
//
#include <hip/hip_runtime.h>
#include <hip/hip_bf16.h>

#define N_NODES 50000
#define N_EDGES 1600000
#define HEADS 8
#define HDIM 16
#define D1 128   // HEADS*HDIM
#define NEG_SLOPE 0.2f
#define SCAN_BLKS 196  // ceil(50000/256)

typedef short short8 __attribute__((ext_vector_type(8)));
typedef float f32x4 __attribute__((ext_vector_type(4)));

// ---- dtype helpers (flag: 1 = buffers are fp32, 0 = bf16) ----
__device__ __forceinline__ float bf2f(ushort u) {
    union { unsigned u; float f; } x; x.u = ((unsigned)u) << 16; return x.f;
}
__device__ __forceinline__ ushort f2bf(float f) {
    union { float f; unsigned u; } x; x.f = f;
    unsigned r = x.u + 0x7FFF + ((x.u >> 16) & 1);   // RNE
    return (ushort)(r >> 16);
}
__device__ __forceinline__ float ldf(const void* p, size_t i, int isf32) {
    return isf32 ? ((const float*)p)[i] : bf2f(((const ushort*)p)[i]);
}

// ---------------- dtype detection ----------------
// W1 has 32768 float elements. Interpreted as bf16 halves of fp32 data, the
// low halves carry random exponents -> values >= 2^73 appear w.p. ~21%/elem.
// Genuine bf16 weights are all < 2: never trigger.
__global__ __launch_bounds__(256) void k_detect(const ushort* __restrict__ w1, int* __restrict__ flags) {
    __shared__ int sm[256];
    int t = threadIdx.x;
    int cnt = 0;
    for (int i = t; i < 32768; i += 256) {
        int e = (w1[i] >> 7) & 0xFF;
        if (e >= 0xC8) cnt++;
    }
    sm[t] = cnt; __syncthreads();
    for (int off = 128; off > 0; off >>= 1) {
        if (t < off) sm[t] += sm[t + off];
        __syncthreads();
    }
    if (t == 0) { flags[0] = (sm[0] > 0) ? 1 : 0; flags[1] = 1; }
}

// ---------------- CSR build ----------------
__global__ __launch_bounds__(256) void k_deg(const int* __restrict__ dst, int* __restrict__ deg) {
    int i = blockIdx.x * 256 + threadIdx.x;
    if (i < N_EDGES) atomicAdd(&deg[dst[i]], 1);
}

__global__ __launch_bounds__(256) void k_scan1(const int* __restrict__ deg, int* __restrict__ tmp, int* __restrict__ bsum) {
    __shared__ int sm[256];
    int t = threadIdx.x;
    int i = blockIdx.x * 256 + t;
    int x = (i < N_NODES) ? deg[i] : 0;
    sm[t] = x; __syncthreads();
    for (int off = 1; off < 256; off <<= 1) {
        int v = (t >= off) ? sm[t - off] : 0;
        __syncthreads();
        sm[t] += v;
        __syncthreads();
    }
    if (i < N_NODES) tmp[i] = sm[t];
    if (t == 255) bsum[blockIdx.x] = sm[255];
}

__global__ __launch_bounds__(256) void k_scan2(const int* __restrict__ bsum, int* __restrict__ boff) {
    __shared__ int sm[256];
    int t = threadIdx.x;
    int x = (t < SCAN_BLKS) ? bsum[t] : 0;
    sm[t] = x; __syncthreads();
    for (int off = 1; off < 256; off <<= 1) {
        int v = (t >= off) ? sm[t - off] : 0;
        __syncthreads();
        sm[t] += v;
        __syncthreads();
    }
    boff[t] = sm[t] - x;   // exclusive
}

__global__ __launch_bounds__(256) void k_scan3(const int* __restrict__ tmp, const int* __restrict__ boff, int* __restrict__ rowptr) {
    int i = blockIdx.x * 256 + threadIdx.x;
    if (i < N_NODES) rowptr[i + 1] = tmp[i] + boff[i >> 8];
    if (i == 0) rowptr[0] = 0;
}

__global__ __launch_bounds__(256) void k_scatter(const int* __restrict__ src, const int* __restrict__ dst,
                                                 const int* __restrict__ rowptr, int* __restrict__ fill,
                                                 int* __restrict__ esrc) {
    int i = blockIdx.x * 256 + threadIdx.x;
    if (i < N_EDGES) {
        int v = dst[i];
        int pos = rowptr[v] + atomicAdd(&fill[v], 1);
        esrc[pos] = src[i];
    }
}

// ---------------- weight split+transpose: W[K][128] -> Whi_t/Wlo_t [128][K] bf16 ----------------
__global__ __launch_bounds__(256) void k_wsplit(const void* __restrict__ W, int K,
                                                ushort* __restrict__ whi, ushort* __restrict__ wlo,
                                                const int* __restrict__ flags) {
    int isf32 = flags[0];
    int idx = blockIdx.x * 256 + threadIdx.x;
    if (idx >= K * 128) return;
    int k = idx >> 7, n = idx & 127;
    float f = ldf(W, idx, isf32);
    ushort hi = f2bf(f);
    float rem = f - bf2f(hi);
    ushort lo = f2bf(rem);
    whi[n * K + k] = hi;
    wlo[n * K + k] = lo;
}

// ---------------- small array convert -> fp32 ----------------
__global__ __launch_bounds__(256) void k_cvt(const void* __restrict__ in, float* __restrict__ out,
                                             int n, const int* __restrict__ flags) {
    int isf32 = flags[0];
    int i = blockIdx.x * 256 + threadIdx.x;
    if (i < n) out[i] = ldf(in, i, isf32);
}

// ---------------- GEMM: C[M][128] = A[M][K] * W[K][128], fp32 out ----------------
// split-bf16: A = Ahi + Alo, 3 MFMAs -> ~fp32 precision.
// one 16x16 tile per wave via mfma_f32_16x16x32_bf16
__global__ __launch_bounds__(256) void k_gemm(const void* __restrict__ A,
                                              const ushort* __restrict__ Bhi, const ushort* __restrict__ Blo,
                                              float* __restrict__ C, int M, int K,
                                              const int* __restrict__ flags) {
    int isf32 = flags[0];
    int wave = threadIdx.x >> 6;
    int lane = threadIdx.x & 63;
    int gid = blockIdx.x * 4 + wave;
    int ntiles = (M >> 4) * 8;
    if (gid >= ntiles) return;
    int rt = gid >> 3, ct = gid & 7;
    int quad = lane >> 4, l16 = lane & 15;
    size_t a_off = (size_t)(rt * 16 + l16) * K + quad * 8;
    const ushort* bhi_base = Bhi + (size_t)(ct * 16 + l16) * K + quad * 8;
    const ushort* blo_base = Blo + (size_t)(ct * 16 + l16) * K + quad * 8;
    f32x4 acc = {0.f, 0.f, 0.f, 0.f};
    for (int kk = 0; kk < K; kk += 32) {
        float a8[8];
        if (isf32) {
            const float* ap = (const float*)A + a_off + kk;
            f32x4 u0 = *(const f32x4*)(ap);
            f32x4 u1 = *(const f32x4*)(ap + 4);
            a8[0] = u0[0]; a8[1] = u0[1]; a8[2] = u0[2]; a8[3] = u0[3];
            a8[4] = u1[0]; a8[5] = u1[1]; a8[6] = u1[2]; a8[7] = u1[3];
        } else {
            short8 s = *(const short8*)((const ushort*)A + a_off + kk);
#pragma unroll
            for (int j = 0; j < 8; ++j) a8[j] = bf2f((ushort)s[j]);
        }
        short8 ahi, alo;
#pragma unroll
        for (int j = 0; j < 8; ++j) {
            ushort h = f2bf(a8[j]);
            ahi[j] = (short)h;
            alo[j] = (short)f2bf(a8[j] - bf2f(h));
        }
        short8 bhi = *(const short8*)(bhi_base + kk);
        short8 blo = *(const short8*)(blo_base + kk);
        acc = __builtin_amdgcn_mfma_f32_16x16x32_bf16(ahi, bhi, acc, 0, 0, 0);
        acc = __builtin_amdgcn_mfma_f32_16x16x32_bf16(ahi, blo, acc, 0, 0, 0);
        acc = __builtin_amdgcn_mfma_f32_16x16x32_bf16(alo, bhi, acc, 0, 0, 0);
    }
    // C/D layout: col = lane&15, row = (lane>>4)*4 + reg
    int row = rt * 16 + quad * 4;
    int col = ct * 16 + l16;
    float* cp = C + (size_t)row * D1 + col;
    cp[0 * D1] = acc[0];
    cp[1 * D1] = acc[1];
    cp[2 * D1] = acc[2];
    cp[3 * D1] = acc[3];
}

// ---------------- el/er: one thread per (node, head) ----------------
__global__ __launch_bounds__(256) void k_elr(const float* __restrict__ feat,
                                             const float* __restrict__ al,
                                             const float* __restrict__ ar,
                                             float* __restrict__ el, float* __restrict__ er) {
    int i = blockIdx.x * 256 + threadIdx.x;
    if (i >= N_NODES * HEADS) return;
    int v = i >> 3, h = i & 7;
    const float* f = feat + (size_t)v * D1 + h * HDIM;
    const float* alh = al + h * HDIM;
    const float* arh = ar + h * HDIM;
    float sl = 0.f, sr = 0.f;
#pragma unroll
    for (int d = 0; d < HDIM; ++d) {
        float x = f[d];
        sl = fmaf(x, alh[d], sl);
        sr = fmaf(x, arh[d], sr);
    }
    el[i] = sl;
    er[i] = sr;
}

// ---------------- aggregate: one block (128 thr) per dst node ----------------
// mode 0: out = elu(agg + bias) -> fp32 [N][128]  (layer-1 h)
// mode 1: out = mean over heads of (agg + bias) -> d_out (bf16 or fp32 per flag)
__global__ __launch_bounds__(128) void k_agg(const int* __restrict__ rowptr, const int* __restrict__ esrc,
                                             const float* __restrict__ feat,
                                             const float* __restrict__ el, const float* __restrict__ er,
                                             const float* __restrict__ bias,
                                             void* __restrict__ out, int mode,
                                             const int* __restrict__ flags) {
    int v = blockIdx.x;
    int c = threadIdx.x;
    int h = c >> 4;
    float erv = er[v * HEADS + h];
    int beg = rowptr[v], end = rowptr[v + 1];
    float acc = 0.f, den = 0.f;
    int j = beg;
    for (; j + 1 < end; j += 2) {
        int s0 = esrc[j], s1 = esrc[j + 1];
        float e0 = el[s0 * HEADS + h];
        float e1 = el[s1 * HEADS + h];
        float f0 = feat[(size_t)s0 * D1 + c];
        float f1 = feat[(size_t)s1 * D1 + c];
        float x0 = e0 + erv; x0 = x0 > 0.f ? x0 : NEG_SLOPE * x0;
        float x1 = e1 + erv; x1 = x1 > 0.f ? x1 : NEG_SLOPE * x1;
        float w0 = __expf(x0);
        float w1 = __expf(x1);
        den += w0 + w1;
        acc = fmaf(w0, f0, acc);
        acc = fmaf(w1, f1, acc);
    }
    if (j < end) {
        int s = esrc[j];
        float e = el[s * HEADS + h];
        float f = feat[(size_t)s * D1 + c];
        float x = e + erv; x = x > 0.f ? x : NEG_SLOPE * x;
        float w = __expf(x);
        den += w;
        acc = fmaf(w, f, acc);
    }
    float res = (end > beg) ? (acc / den) : 0.f;
    res += bias[c];
    if (mode == 0) {
        res = res > 0.f ? res : (__expf(res) - 1.f);   // ELU
        ((float*)out)[(size_t)v * D1 + c] = res;
    } else {
        __shared__ float sm[128];
        sm[c] = res;
        __syncthreads();
        if (c < HDIM) {
            float s = 0.f;
#pragma unroll
            for (int hh = 0; hh < HEADS; ++hh) s += sm[hh * HDIM + c];
            float val = s * 0.125f;
            if (flags[0]) ((float*)out)[(size_t)v * HDIM + c] = val;
            else ((ushort*)out)[(size_t)v * HDIM + c] = f2bf(val);
        }
    }
}

// ---------------- workspace layout (bytes) ----------------
#define O_ROWPTR   0              // 200064
#define O_DEG      200064         // 200000
#define O_FILL     400064         // 200000  (contiguous with DEG for one memset)
#define O_BSUM     600064         // 4096
#define O_BOFF     604160         // 4096
#define O_TMPSCAN  608256         // 200000
#define O_FLAGS    808256         // 256
#define O_ESRC     808512         // 6,400,000
#define O_W1HI     7208512        // 65536
#define O_W1LO     7274048        // 65536
#define O_W2HI     7339584        // 32768
#define O_W2LO     7372352        // 32768
#define O_AL1F     7405120        // 512
#define O_AR1F     7405632        // 512
#define O_B1F      7406144        // 512
#define O_AL2F     7406656        // 512
#define O_AR2F     7407168        // 512
#define O_B2F      7407680        // 512
#define O_FEAT     7408256        // 25,600,000 (fp32, reused by both layers)
#define O_EL       33008256       // 1,600,000
#define O_ER       34608256       // 1,600,000
#define O_H        36208256       // 25,600,000 (fp32 layer-1 output)
// total ~61.8 MB

extern "C" void kernel_launch(void* const* d_in, const int* in_sizes, int n_in,
                              void* d_out, int out_size, void* d_ws, size_t ws_size,
                              hipStream_t stream) {
    const void* node_feat = d_in[0];
    const int* src = (const int*)d_in[1];
    const int* dst = (const int*)d_in[2];
    const void* W1 = d_in[3];
    const void* al1 = d_in[4];
    const void* ar1 = d_in[5];
    const void* b1 = d_in[6];
    const void* W2 = d_in[7];
    const void* al2 = d_in[8];
    const void* ar2 = d_in[9];
    const void* b2 = d_in[10];

    char* ws = (char*)d_ws;
    int* rowptr = (int*)(ws + O_ROWPTR);
    int* deg    = (int*)(ws + O_DEG);
    int* fill   = (int*)(ws + O_FILL);
    int* bsum   = (int*)(ws + O_BSUM);
    int* boff   = (int*)(ws + O_BOFF);
    int* tmpsc  = (int*)(ws + O_TMPSCAN);
    int* flags  = (int*)(ws + O_FLAGS);
    int* esrc   = (int*)(ws + O_ESRC);
    ushort* w1hi = (ushort*)(ws + O_W1HI);
    ushort* w1lo = (ushort*)(ws + O_W1LO);
    ushort* w2hi = (ushort*)(ws + O_W2HI);
    ushort* w2lo = (ushort*)(ws + O_W2LO);
    float* al1f = (float*)(ws + O_AL1F);
    float* ar1f = (float*)(ws + O_AR1F);
    float* b1f  = (float*)(ws + O_B1F);
    float* al2f = (float*)(ws + O_AL2F);
    float* ar2f = (float*)(ws + O_AR2F);
    float* b2f  = (float*)(ws + O_B2F);
    float* feat = (float*)(ws + O_FEAT);
    float* el   = (float*)(ws + O_EL);
    float* er   = (float*)(ws + O_ER);
    float* hbuf = (float*)(ws + O_H);

    const int EB = (N_EDGES + 255) / 256;       // 6250
    const int NHB = (N_NODES * HEADS + 255) / 256;

    // dtype detection (must precede every flag reader)
    k_detect<<<1, 256, 0, stream>>>((const ushort*)W1, flags);

    // CSR build
    hipMemsetAsync(ws + O_DEG, 0, 2 * N_NODES * 4, stream);   // deg + fill
    k_deg<<<EB, 256, 0, stream>>>(dst, deg);
    k_scan1<<<SCAN_BLKS, 256, 0, stream>>>(deg, tmpsc, bsum);
    k_scan2<<<1, 256, 0, stream>>>(bsum, boff);
    k_scan3<<<SCAN_BLKS, 256, 0, stream>>>(tmpsc, boff, rowptr);
    k_scatter<<<EB, 256, 0, stream>>>(src, dst, rowptr, fill, esrc);

    // weight split+transpose, small-array converts
    k_wsplit<<<128, 256, 0, stream>>>(W1, 256, w1hi, w1lo, flags);
    k_wsplit<<<64, 256, 0, stream>>>(W2, 128, w2hi, w2lo, flags);
    k_cvt<<<1, 256, 0, stream>>>(al1, al1f, 128, flags);
    k_cvt<<<1, 256, 0, stream>>>(ar1, ar1f, 128, flags);
    k_cvt<<<1, 256, 0, stream>>>(b1, b1f, 128, flags);
    k_cvt<<<1, 256, 0, stream>>>(al2, al2f, 128, flags);
    k_cvt<<<1, 256, 0, stream>>>(ar2, ar2f, 128, flags);
    k_cvt<<<1, 256, 0, stream>>>(b2, b2f, 128, flags);

    // layer 1
    k_gemm<<<(N_NODES / 16) * 8 / 4, 256, 0, stream>>>(node_feat, w1hi, w1lo, feat, N_NODES, 256, flags);
    k_elr<<<NHB, 256, 0, stream>>>(feat, al1f, ar1f, el, er);
    k_agg<<<N_NODES, 128, 0, stream>>>(rowptr, esrc, feat, el, er, b1f, hbuf, 0, flags);

    // layer 2 (h is our own fp32 buffer -> flags+1 is the constant "fp32" flag)
    k_gemm<<<(N_NODES / 16) * 8 / 4, 256, 0, stream>>>(hbuf, w2hi, w2lo, feat, N_NODES, 128, flags + 1);
    k_elr<<<NHB, 256, 0, stream>>>(feat, al2f, ar2f, el, er);
    k_agg<<<N_NODES, 128, 0, stream>>>(rowptr, esrc, feat, el, er, b2f, (void*)d_out, 1, flags);
}

// Round 3
// 620.626 us; speedup vs baseline: 1.1030x; 1.1030x over previous
//
#include <hip/hip_runtime.h>
#include <hip/hip_bf16.h>

#define N_NODES 50000
#define N_EDGES 1600000
#define HEADS 8
#define HDIM 16
#define D1 128   // HEADS*HDIM
#define NEG_SLOPE 0.2f
#define SCAN_BLKS 196  // ceil(50000/256)

typedef short short8 __attribute__((ext_vector_type(8)));
typedef float f32x4 __attribute__((ext_vector_type(4)));
typedef _Float16 half2v __attribute__((ext_vector_type(2)));

// ---- dtype helpers (flag: 1 = buffers are fp32, 0 = bf16) ----
__device__ __forceinline__ float bf2f(ushort u) {
    union { unsigned u; float f; } x; x.u = ((unsigned)u) << 16; return x.f;
}
__device__ __forceinline__ ushort f2bf(float f) {
    union { float f; unsigned u; } x; x.f = f;
    unsigned r = x.u + 0x7FFF + ((x.u >> 16) & 1);   // RNE
    return (ushort)(r >> 16);
}
__device__ __forceinline__ float ldf(const void* p, size_t i, int isf32) {
    return isf32 ? ((const float*)p)[i] : bf2f(((const ushort*)p)[i]);
}

// ---------------- dtype detection ----------------
__global__ __launch_bounds__(256) void k_detect(const ushort* __restrict__ w1, int* __restrict__ flags) {
    __shared__ int sm[256];
    int t = threadIdx.x;
    int cnt = 0;
    for (int i = t; i < 32768; i += 256) {
        int e = (w1[i] >> 7) & 0xFF;
        if (e >= 0xC8) cnt++;
    }
    sm[t] = cnt; __syncthreads();
    for (int off = 128; off > 0; off >>= 1) {
        if (t < off) sm[t] += sm[t + off];
        __syncthreads();
    }
    if (t == 0) { flags[0] = (sm[0] > 0) ? 1 : 0; flags[1] = 1; }
}

// ---------------- CSR build ----------------
__global__ __launch_bounds__(256) void k_deg(const int* __restrict__ dst, int* __restrict__ deg) {
    int i = blockIdx.x * 256 + threadIdx.x;
    if (i < N_EDGES) atomicAdd(&deg[dst[i]], 1);
}

__global__ __launch_bounds__(256) void k_scan1(const int* __restrict__ deg, int* __restrict__ tmp, int* __restrict__ bsum) {
    __shared__ int sm[256];
    int t = threadIdx.x;
    int i = blockIdx.x * 256 + t;
    int x = (i < N_NODES) ? deg[i] : 0;
    sm[t] = x; __syncthreads();
    for (int off = 1; off < 256; off <<= 1) {
        int v = (t >= off) ? sm[t - off] : 0;
        __syncthreads();
        sm[t] += v;
        __syncthreads();
    }
    if (i < N_NODES) tmp[i] = sm[t];
    if (t == 255) bsum[blockIdx.x] = sm[255];
}

__global__ __launch_bounds__(256) void k_scan2(const int* __restrict__ bsum, int* __restrict__ boff) {
    __shared__ int sm[256];
    int t = threadIdx.x;
    int x = (t < SCAN_BLKS) ? bsum[t] : 0;
    sm[t] = x; __syncthreads();
    for (int off = 1; off < 256; off <<= 1) {
        int v = (t >= off) ? sm[t - off] : 0;
        __syncthreads();
        sm[t] += v;
        __syncthreads();
    }
    boff[t] = sm[t] - x;   // exclusive
}

__global__ __launch_bounds__(256) void k_scan3(const int* __restrict__ tmp, const int* __restrict__ boff, int* __restrict__ rowptr) {
    int i = blockIdx.x * 256 + threadIdx.x;
    if (i < N_NODES) rowptr[i + 1] = tmp[i] + boff[i >> 8];
    if (i == 0) rowptr[0] = 0;
}

__global__ __launch_bounds__(256) void k_scatter(const int* __restrict__ src, const int* __restrict__ dst,
                                                 const int* __restrict__ rowptr, int* __restrict__ fill,
                                                 int* __restrict__ esrc) {
    int i = blockIdx.x * 256 + threadIdx.x;
    if (i < N_EDGES) {
        int v = dst[i];
        int pos = rowptr[v] + atomicAdd(&fill[v], 1);
        esrc[pos] = src[i];
    }
}

// ---- extended weight prep: Bt[144][K] (bf16 hi/lo), transposed.
// rows 0..127  = W columns;  rows 128..135 = W @ al (el fold);  136..143 = W @ ar.
// (X W) . al == X (W al)  -> el/er drop out of the GEMM epilogue exactly.
__global__ __launch_bounds__(256) void k_wprep(const void* __restrict__ W, const void* __restrict__ al,
                                               const void* __restrict__ ar, int K, int kshift,
                                               ushort* __restrict__ whi, ushort* __restrict__ wlo,
                                               const int* __restrict__ flags) {
    int isf32 = flags[0];
    int idx = blockIdx.x * 256 + threadIdx.x;
    if (idx >= 144 * K) return;
    int n = idx >> kshift, k = idx & (K - 1);
    float f;
    if (n < 128) {
        f = ldf(W, (size_t)k * 128 + n, isf32);
    } else if (n < 136) {
        int h = n - 128;
        f = 0.f;
#pragma unroll
        for (int d = 0; d < HDIM; ++d)
            f = fmaf(ldf(W, (size_t)k * 128 + h * 16 + d, isf32), ldf(al, h * 16 + d, isf32), f);
    } else {
        int h = n - 136;
        f = 0.f;
#pragma unroll
        for (int d = 0; d < HDIM; ++d)
            f = fmaf(ldf(W, (size_t)k * 128 + h * 16 + d, isf32), ldf(ar, h * 16 + d, isf32), f);
    }
    ushort hi = f2bf(f);
    wlo[n * K + k] = f2bf(f - bf2f(hi));
    whi[n * K + k] = hi;
}

// ---------------- small array convert -> fp32 ----------------
__global__ __launch_bounds__(256) void k_cvt(const void* __restrict__ in, float* __restrict__ out,
                                             int n, const int* __restrict__ flags) {
    int isf32 = flags[0];
    int i = blockIdx.x * 256 + threadIdx.x;
    if (i < n) out[i] = ldf(in, i, isf32);
}

// ---------------- GEMM: one wave per 16-row panel, all 9 col tiles ----------------
// feat -> fp16 [M][128]; el/er -> fp32 [M][8] from the folded tile (ct=8).
__global__ __launch_bounds__(256) void k_gemm(const void* __restrict__ A,
                                              const ushort* __restrict__ Bhi, const ushort* __restrict__ Blo,
                                              _Float16* __restrict__ featg,
                                              float* __restrict__ el, float* __restrict__ er,
                                              int M, int K,
                                              const int* __restrict__ flags) {
    int isf32 = flags[0];
    int wave = threadIdx.x >> 6;
    int lane = threadIdx.x & 63;
    int rt = blockIdx.x * 4 + wave;
    if (rt * 16 >= M) return;
    int quad = lane >> 4, l16 = lane & 15;
    size_t a_off = (size_t)(rt * 16 + l16) * K + quad * 8;
    const ushort* bh = Bhi + (size_t)l16 * K + quad * 8;
    const ushort* bl = Blo + (size_t)l16 * K + quad * 8;
    f32x4 acc[9];
#pragma unroll
    for (int c = 0; c < 9; ++c) acc[c] = (f32x4){0.f, 0.f, 0.f, 0.f};
    for (int kk = 0; kk < K; kk += 32) {
        float a8[8];
        if (isf32) {
            const float* ap = (const float*)A + a_off + kk;
            f32x4 u0 = *(const f32x4*)(ap);
            f32x4 u1 = *(const f32x4*)(ap + 4);
            a8[0] = u0[0]; a8[1] = u0[1]; a8[2] = u0[2]; a8[3] = u0[3];
            a8[4] = u1[0]; a8[5] = u1[1]; a8[6] = u1[2]; a8[7] = u1[3];
        } else {
            short8 s = *(const short8*)((const ushort*)A + a_off + kk);
#pragma unroll
            for (int j = 0; j < 8; ++j) a8[j] = bf2f((ushort)s[j]);
        }
        short8 ahi, alo;
#pragma unroll
        for (int j = 0; j < 8; ++j) {
            ushort h = f2bf(a8[j]);
            ahi[j] = (short)h;
            alo[j] = (short)f2bf(a8[j] - bf2f(h));
        }
#pragma unroll
        for (int c = 0; c < 9; ++c) {
            short8 bhi8 = *(const short8*)(bh + (size_t)c * 16 * K + kk);
            short8 blo8 = *(const short8*)(bl + (size_t)c * 16 * K + kk);
            acc[c] = __builtin_amdgcn_mfma_f32_16x16x32_bf16(ahi, bhi8, acc[c], 0, 0, 0);
            acc[c] = __builtin_amdgcn_mfma_f32_16x16x32_bf16(ahi, blo8, acc[c], 0, 0, 0);
            acc[c] = __builtin_amdgcn_mfma_f32_16x16x32_bf16(alo, bhi8, acc[c], 0, 0, 0);
        }
    }
    // C/D layout: col = lane&15, row = (lane>>4)*4 + reg
    int rowb = rt * 16 + quad * 4;
#pragma unroll
    for (int c = 0; c < 8; ++c) {
        int col = c * 16 + l16;
#pragma unroll
        for (int r = 0; r < 4; ++r)
            featg[(size_t)(rowb + r) * D1 + col] = (_Float16)acc[c][r];
    }
#pragma unroll
    for (int r = 0; r < 4; ++r) {
        float vv = acc[8][r];
        int row = rowb + r;
        if (l16 < 8) el[row * 8 + l16] = vv;
        else         er[row * 8 + (l16 - 8)] = vv;
    }
}

// ---------------- aggregate: one wave per dst node, 2 channels/lane ----------------
// mode 0: out = elu(agg + bias) -> fp32 [N][128]  (layer-1 h)
// mode 1: out = mean over heads of (agg + bias) -> d_out (bf16 or fp32 per flag)
__global__ __launch_bounds__(256) void k_agg(const int* __restrict__ rowptr, const int* __restrict__ esrc,
                                             const half2v* __restrict__ featg,
                                             const float* __restrict__ el, const float* __restrict__ er,
                                             const float* __restrict__ bias,
                                             void* __restrict__ out, int mode,
                                             const int* __restrict__ flags) {
    int wv = threadIdx.x >> 6;
    int lane = threadIdx.x & 63;
    int v = blockIdx.x * 4 + wv;
    if (v >= N_NODES) return;
    int hsel = lane & 7;           // head index computed by this lane (lanes 0-7 authoritative)
    int lsrc = lane >> 3;          // broadcast source: lane's own head = lane>>3
    float erv = er[v * 8 + hsel];
    int beg = rowptr[v], end = rowptr[v + 1];
    float acc0 = 0.f, acc1 = 0.f, den = 0.f;
    int j = beg;
    for (; j + 1 < end; j += 2) {
        int s0 = esrc[j], s1 = esrc[j + 1];
        float x0 = el[s0 * 8 + hsel] + erv;
        float x1 = el[s1 * 8 + hsel] + erv;
        half2v h0 = featg[(size_t)s0 * 64 + lane];
        half2v h1 = featg[(size_t)s1 * 64 + lane];
        x0 = x0 > 0.f ? x0 : NEG_SLOPE * x0;
        x1 = x1 > 0.f ? x1 : NEG_SLOPE * x1;
        float w0 = __shfl(__expf(x0), lsrc);
        float w1 = __shfl(__expf(x1), lsrc);
        den += w0 + w1;
        acc0 = fmaf(w0, (float)h0[0], acc0);
        acc1 = fmaf(w0, (float)h0[1], acc1);
        acc0 = fmaf(w1, (float)h1[0], acc0);
        acc1 = fmaf(w1, (float)h1[1], acc1);
    }
    if (j < end) {
        int s = esrc[j];
        float x = el[s * 8 + hsel] + erv;
        half2v h = featg[(size_t)s * 64 + lane];
        x = x > 0.f ? x : NEG_SLOPE * x;
        float w = __shfl(__expf(x), lsrc);
        den += w;
        acc0 = fmaf(w, (float)h[0], acc0);
        acc1 = fmaf(w, (float)h[1], acc1);
    }
    float inv = (end > beg) ? 1.0f / den : 0.f;
    float2 bb = ((const float2*)bias)[lane];
    float r0 = fmaf(acc0, inv, bb.x);
    float r1 = fmaf(acc1, inv, bb.y);
    if (mode == 0) {
        r0 = r0 > 0.f ? r0 : (__expf(r0) - 1.f);   // ELU
        r1 = r1 > 0.f ? r1 : (__expf(r1) - 1.f);
        float2 st = {r0, r1};
        ((float2*)out)[(size_t)v * 64 + lane] = st;
    } else {
        // mean over heads: lanes sharing (lane&7) hold the same dims of different heads
        for (int m = 8; m < 64; m <<= 1) {
            r0 += __shfl_xor(r0, m);
            r1 += __shfl_xor(r1, m);
        }
        if (lane < 8) {
            float v0 = r0 * 0.125f, v1 = r1 * 0.125f;
            if (flags[0]) {
                float2 st = {v0, v1};
                ((float2*)out)[(size_t)v * 8 + lane] = st;
            } else {
                unsigned pk = (unsigned)f2bf(v0) | ((unsigned)f2bf(v1) << 16);
                ((unsigned*)out)[(size_t)v * 8 + lane] = pk;
            }
        }
    }
}

// ---------------- workspace layout (bytes) ----------------
#define O_ROWPTR   0              // 200064
#define O_DEG      200064         // 200000
#define O_FILL     400064         // 200000  (contiguous with DEG for one memset)
#define O_BSUM     600064         // 4096
#define O_BOFF     604160         // 4096
#define O_TMPSCAN  608256         // 200064
#define O_FLAGS    808320         // 256
#define O_ESRC     808576         // 6,400,000
#define O_W1HI     7208576        // 147456 (144 x 256 bf16)
#define O_W1LO     7356032        // 147456
#define O_W2HI     7503488        // 73728  (144 x 128 bf16)
#define O_W2LO     7577216        // 73728
#define O_B1F      7650944        // 512
#define O_B2F      7651456        // 512
#define O_FEATG    7651968        // 12,800,000 (fp16 [N][128], reused by both layers)
#define O_EL       20451968       // 1,600,000
#define O_ER       22051968       // 1,600,000
#define O_H        23651968       // 25,600,000 (fp32 layer-1 output)
// total ~49.3 MB

extern "C" void kernel_launch(void* const* d_in, const int* in_sizes, int n_in,
                              void* d_out, int out_size, void* d_ws, size_t ws_size,
                              hipStream_t stream) {
    const void* node_feat = d_in[0];
    const int* src = (const int*)d_in[1];
    const int* dst = (const int*)d_in[2];
    const void* W1 = d_in[3];
    const void* al1 = d_in[4];
    const void* ar1 = d_in[5];
    const void* b1 = d_in[6];
    const void* W2 = d_in[7];
    const void* al2 = d_in[8];
    const void* ar2 = d_in[9];
    const void* b2 = d_in[10];

    char* ws = (char*)d_ws;
    int* rowptr = (int*)(ws + O_ROWPTR);
    int* deg    = (int*)(ws + O_DEG);
    int* fill   = (int*)(ws + O_FILL);
    int* bsum   = (int*)(ws + O_BSUM);
    int* boff   = (int*)(ws + O_BOFF);
    int* tmpsc  = (int*)(ws + O_TMPSCAN);
    int* flags  = (int*)(ws + O_FLAGS);
    int* esrc   = (int*)(ws + O_ESRC);
    ushort* w1hi = (ushort*)(ws + O_W1HI);
    ushort* w1lo = (ushort*)(ws + O_W1LO);
    ushort* w2hi = (ushort*)(ws + O_W2HI);
    ushort* w2lo = (ushort*)(ws + O_W2LO);
    float* b1f  = (float*)(ws + O_B1F);
    float* b2f  = (float*)(ws + O_B2F);
    _Float16* featg = (_Float16*)(ws + O_FEATG);
    float* el   = (float*)(ws + O_EL);
    float* er   = (float*)(ws + O_ER);
    float* hbuf = (float*)(ws + O_H);

    const int EB = (N_EDGES + 255) / 256;       // 6250
    const int GB = (3125 + 3) / 4;              // gemm blocks: 3125 row-tiles, 4 waves/block

    // dtype detection (must precede every flag reader)
    k_detect<<<1, 256, 0, stream>>>((const ushort*)W1, flags);

    // CSR build
    hipMemsetAsync(ws + O_DEG, 0, 2 * N_NODES * 4, stream);   // deg + fill
    k_deg<<<EB, 256, 0, stream>>>(dst, deg);
    k_scan1<<<SCAN_BLKS, 256, 0, stream>>>(deg, tmpsc, bsum);
    k_scan2<<<1, 256, 0, stream>>>(bsum, boff);
    k_scan3<<<SCAN_BLKS, 256, 0, stream>>>(tmpsc, boff, rowptr);
    k_scatter<<<EB, 256, 0, stream>>>(src, dst, rowptr, fill, esrc);

    // extended weight prep (al/ar folded in), bias converts
    k_wprep<<<(144 * 256 + 255) / 256, 256, 0, stream>>>(W1, al1, ar1, 256, 8, w1hi, w1lo, flags);
    k_wprep<<<(144 * 128 + 255) / 256, 256, 0, stream>>>(W2, al2, ar2, 128, 7, w2hi, w2lo, flags);
    k_cvt<<<1, 256, 0, stream>>>(b1, b1f, 128, flags);
    k_cvt<<<1, 256, 0, stream>>>(b2, b2f, 128, flags);

    // layer 1
    k_gemm<<<GB, 256, 0, stream>>>(node_feat, w1hi, w1lo, featg, el, er, N_NODES, 256, flags);
    k_agg<<<(N_NODES + 3) / 4, 256, 0, stream>>>(rowptr, esrc, (const half2v*)featg, el, er, b1f, hbuf, 0, flags);

    // layer 2 (hbuf is our own fp32 buffer -> flags+1 is the constant "fp32" flag)
    k_gemm<<<GB, 256, 0, stream>>>(hbuf, w2hi, w2lo, featg, el, er, N_NODES, 128, flags + 1);
    k_agg<<<(N_NODES + 3) / 4, 256, 0, stream>>>(rowptr, esrc, (const half2v*)featg, el, er, b2f, (void*)d_out, 1, flags);
}

// Round 4
// 553.186 us; speedup vs baseline: 1.2375x; 1.1219x over previous
//
#include <hip/hip_runtime.h>
#include <hip/hip_bf16.h>

#define N_NODES 50000
#define N_EDGES 1600000
#define HEADS 8
#define HDIM 16
#define D1 128   // HEADS*HDIM
#define NEG_SLOPE 0.2f
#define SCAN_BLKS 196  // ceil(50000/256)

typedef short short8 __attribute__((ext_vector_type(8)));
typedef float f32x4 __attribute__((ext_vector_type(4)));
typedef _Float16 half2v __attribute__((ext_vector_type(2)));

// ---- dtype helpers (flag: 1 = buffers are fp32, 0 = bf16) ----
__device__ __forceinline__ float bf2f(ushort u) {
    union { unsigned u; float f; } x; x.u = ((unsigned)u) << 16; return x.f;
}
__device__ __forceinline__ ushort f2bf(float f) {
    union { float f; unsigned u; } x; x.f = f;
    unsigned r = x.u + 0x7FFF + ((x.u >> 16) & 1);   // RNE
    return (ushort)(r >> 16);
}
__device__ __forceinline__ float ldf(const void* p, size_t i, int isf32) {
    return isf32 ? ((const float*)p)[i] : bf2f(((const ushort*)p)[i]);
}

// ---------------- dtype detection ----------------
__global__ __launch_bounds__(256) void k_detect(const ushort* __restrict__ w1, int* __restrict__ flags) {
    __shared__ int sm[256];
    int t = threadIdx.x;
    int cnt = 0;
    for (int i = t; i < 32768; i += 256) {
        int e = (w1[i] >> 7) & 0xFF;
        if (e >= 0xC8) cnt++;
    }
    sm[t] = cnt; __syncthreads();
    for (int off = 128; off > 0; off >>= 1) {
        if (t < off) sm[t] += sm[t + off];
        __syncthreads();
    }
    if (t == 0) { flags[0] = (sm[0] > 0) ? 1 : 0; flags[1] = 1; }
}

// ---------------- CSR build: ONE atomic pass ----------------
// pos[i] = rank of edge i among edges with same dst (any order is fine).
__global__ __launch_bounds__(256) void k_count(const int* __restrict__ dst, int* __restrict__ deg,
                                               int* __restrict__ pos) {
    int i = blockIdx.x * 256 + threadIdx.x;
    if (i < N_EDGES) pos[i] = atomicAdd(&deg[dst[i]], 1);
}

__global__ __launch_bounds__(256) void k_scan1(const int* __restrict__ deg, int* __restrict__ tmp, int* __restrict__ bsum) {
    __shared__ int sm[256];
    int t = threadIdx.x;
    int i = blockIdx.x * 256 + t;
    int x = (i < N_NODES) ? deg[i] : 0;
    sm[t] = x; __syncthreads();
    for (int off = 1; off < 256; off <<= 1) {
        int v = (t >= off) ? sm[t - off] : 0;
        __syncthreads();
        sm[t] += v;
        __syncthreads();
    }
    if (i < N_NODES) tmp[i] = sm[t];
    if (t == 255) bsum[blockIdx.x] = sm[255];
}

__global__ __launch_bounds__(256) void k_scan2(const int* __restrict__ bsum, int* __restrict__ boff) {
    __shared__ int sm[256];
    int t = threadIdx.x;
    int x = (t < SCAN_BLKS) ? bsum[t] : 0;
    sm[t] = x; __syncthreads();
    for (int off = 1; off < 256; off <<= 1) {
        int v = (t >= off) ? sm[t - off] : 0;
        __syncthreads();
        sm[t] += v;
        __syncthreads();
    }
    boff[t] = sm[t] - x;   // exclusive
}

__global__ __launch_bounds__(256) void k_scan3(const int* __restrict__ tmp, const int* __restrict__ boff, int* __restrict__ rowptr) {
    int i = blockIdx.x * 256 + threadIdx.x;
    if (i < N_NODES) rowptr[i + 1] = tmp[i] + boff[i >> 8];
    if (i == 0) rowptr[0] = 0;
}

// place pass: NO atomics (rank precomputed)
__global__ __launch_bounds__(256) void k_place(const int* __restrict__ src, const int* __restrict__ dst,
                                               const int* __restrict__ rowptr, const int* __restrict__ pos,
                                               int* __restrict__ esrc) {
    int i = blockIdx.x * 256 + threadIdx.x;
    if (i < N_EDGES) {
        int v = dst[i];
        esrc[rowptr[v] + pos[i]] = src[i];
    }
}

// ---- extended weight prep: Bt[144][K] (bf16 hi/lo), transposed.
// rows 0..127 = W columns; 128..135 = W@al (el fold); 136..143 = W@ar.
__global__ __launch_bounds__(256) void k_wprep(const void* __restrict__ W, const void* __restrict__ al,
                                               const void* __restrict__ ar, int K, int kshift,
                                               ushort* __restrict__ whi, ushort* __restrict__ wlo,
                                               const int* __restrict__ flags) {
    int isf32 = flags[0];
    int idx = blockIdx.x * 256 + threadIdx.x;
    if (idx >= 144 * K) return;
    int n = idx >> kshift, k = idx & (K - 1);
    float f;
    if (n < 128) {
        f = ldf(W, (size_t)k * 128 + n, isf32);
    } else if (n < 136) {
        int h = n - 128;
        f = 0.f;
#pragma unroll
        for (int d = 0; d < HDIM; ++d)
            f = fmaf(ldf(W, (size_t)k * 128 + h * 16 + d, isf32), ldf(al, h * 16 + d, isf32), f);
    } else {
        int h = n - 136;
        f = 0.f;
#pragma unroll
        for (int d = 0; d < HDIM; ++d)
            f = fmaf(ldf(W, (size_t)k * 128 + h * 16 + d, isf32), ldf(ar, h * 16 + d, isf32), f);
    }
    ushort hi = f2bf(f);
    wlo[n * K + k] = f2bf(f - bf2f(hi));
    whi[n * K + k] = hi;
}

// ---------------- bias convert (both layers in one launch) ----------------
__global__ __launch_bounds__(256) void k_cvt2(const void* __restrict__ b1, const void* __restrict__ b2,
                                              float* __restrict__ o1, float* __restrict__ o2,
                                              const int* __restrict__ flags) {
    int isf32 = flags[0];
    int i = threadIdx.x;
    if (i < 128) o1[i] = ldf(b1, i, isf32);
    else o2[i - 128] = ldf(b2, i - 128, isf32);
}

// ---------------- GEMM: one wave per 16-row panel, all 9 col tiles ----------------
__global__ __launch_bounds__(256) void k_gemm(const void* __restrict__ A,
                                              const ushort* __restrict__ Bhi, const ushort* __restrict__ Blo,
                                              _Float16* __restrict__ featg,
                                              float* __restrict__ el, float* __restrict__ er,
                                              int M, int K,
                                              const int* __restrict__ flags) {
    int isf32 = flags[0];
    int wave = threadIdx.x >> 6;
    int lane = threadIdx.x & 63;
    int rt = blockIdx.x * 4 + wave;
    if (rt * 16 >= M) return;
    int quad = lane >> 4, l16 = lane & 15;
    size_t a_off = (size_t)(rt * 16 + l16) * K + quad * 8;
    const ushort* bh = Bhi + (size_t)l16 * K + quad * 8;
    const ushort* bl = Blo + (size_t)l16 * K + quad * 8;
    f32x4 acc[9];
#pragma unroll
    for (int c = 0; c < 9; ++c) acc[c] = (f32x4){0.f, 0.f, 0.f, 0.f};
    for (int kk = 0; kk < K; kk += 32) {
        float a8[8];
        if (isf32) {
            const float* ap = (const float*)A + a_off + kk;
            f32x4 u0 = *(const f32x4*)(ap);
            f32x4 u1 = *(const f32x4*)(ap + 4);
            a8[0] = u0[0]; a8[1] = u0[1]; a8[2] = u0[2]; a8[3] = u0[3];
            a8[4] = u1[0]; a8[5] = u1[1]; a8[6] = u1[2]; a8[7] = u1[3];
        } else {
            short8 s = *(const short8*)((const ushort*)A + a_off + kk);
#pragma unroll
            for (int j = 0; j < 8; ++j) a8[j] = bf2f((ushort)s[j]);
        }
        short8 ahi, alo;
#pragma unroll
        for (int j = 0; j < 8; ++j) {
            ushort h = f2bf(a8[j]);
            ahi[j] = (short)h;
            alo[j] = (short)f2bf(a8[j] - bf2f(h));
        }
#pragma unroll
        for (int c = 0; c < 9; ++c) {
            short8 bhi8 = *(const short8*)(bh + (size_t)c * 16 * K + kk);
            short8 blo8 = *(const short8*)(bl + (size_t)c * 16 * K + kk);
            acc[c] = __builtin_amdgcn_mfma_f32_16x16x32_bf16(ahi, bhi8, acc[c], 0, 0, 0);
            acc[c] = __builtin_amdgcn_mfma_f32_16x16x32_bf16(ahi, blo8, acc[c], 0, 0, 0);
            acc[c] = __builtin_amdgcn_mfma_f32_16x16x32_bf16(alo, bhi8, acc[c], 0, 0, 0);
        }
    }
    // C/D layout: col = lane&15, row = (lane>>4)*4 + reg
    int rowb = rt * 16 + quad * 4;
#pragma unroll
    for (int c = 0; c < 8; ++c) {
        int col = c * 16 + l16;
#pragma unroll
        for (int r = 0; r < 4; ++r)
            featg[(size_t)(rowb + r) * D1 + col] = (_Float16)acc[c][r];
    }
#pragma unroll
    for (int r = 0; r < 4; ++r) {
        float vv = acc[8][r];
        int row = rowb + r;
        if (l16 < 8) el[row * 8 + l16] = vv;
        else         er[row * 8 + (l16 - 8)] = vv;
    }
}

// ---------------- aggregate: one wave per dst node, batch-8 edges ----------------
// Lane L computes the logit for (edge j+L>>3, head L&7): one leaky+exp per 8 edges.
// Then per edge e: weight for consumer lane i (head i>>3) sits in lane e*8+(i>>3).
__global__ __launch_bounds__(256) void k_agg(const int* __restrict__ rowptr, const int* __restrict__ esrc,
                                             const half2v* __restrict__ featg,
                                             const float* __restrict__ el, const float* __restrict__ er,
                                             const float* __restrict__ bias,
                                             void* __restrict__ out, int mode,
                                             const int* __restrict__ flags) {
    int wv = threadIdx.x >> 6;
    int lane = threadIdx.x & 63;
    int v = blockIdx.x * 4 + wv;
    if (v >= N_NODES) return;
    int h8 = lane & 7;            // logit head for this lane
    int esel = lane >> 3;         // logit edge-in-batch for this lane; also consumer head
    float erv = er[v * 8 + h8];
    int beg = rowptr[v], end = rowptr[v + 1];
    float acc0 = 0.f, acc1 = 0.f, den = 0.f;
    for (int j = beg; j < end; j += 8) {
        int rem = end - j;                 // wave-uniform
        int idx = j + h8;
        if (idx > end - 1) idx = end - 1;  // clamp (loop body implies end>beg)
        int sv = esrc[idx];                // lane L holds src of edge j+(L&7)
        // logits: edge j+esel, head h8
        int se = __shfl(sv, esel);
        float x = el[se * 8 + h8] + erv;
        x = x > 0.f ? x : NEG_SLOPE * x;
        float w = __expf(x);               // lane e*8+m holds weight(edge j+e, head m)
#pragma unroll
        for (int e = 0; e < 8; ++e) {
            if (e >= rem) break;           // uniform branch
            float we = __shfl(w, e * 8 + esel);
            int s = __shfl(sv, e);
            half2v hh = featg[(size_t)s * 64 + lane];
            den += we;
            acc0 = fmaf(we, (float)hh[0], acc0);
            acc1 = fmaf(we, (float)hh[1], acc1);
        }
    }
    float inv = (end > beg) ? 1.0f / den : 0.f;
    float2 bb = ((const float2*)bias)[lane];
    float r0 = fmaf(acc0, inv, bb.x);
    float r1 = fmaf(acc1, inv, bb.y);
    if (mode == 0) {
        r0 = r0 > 0.f ? r0 : (__expf(r0) - 1.f);   // ELU
        r1 = r1 > 0.f ? r1 : (__expf(r1) - 1.f);
        float2 st = {r0, r1};
        ((float2*)out)[(size_t)v * 64 + lane] = st;
    } else {
        // mean over heads: lanes i, i^8, i^16, i^32 hold same channels of different heads
        for (int m = 8; m < 64; m <<= 1) {
            r0 += __shfl_xor(r0, m);
            r1 += __shfl_xor(r1, m);
        }
        if (lane < 8) {
            float v0 = r0 * 0.125f, v1 = r1 * 0.125f;
            if (flags[0]) {
                float2 st = {v0, v1};
                ((float2*)out)[(size_t)v * 8 + lane] = st;
            } else {
                unsigned pk = (unsigned)f2bf(v0) | ((unsigned)f2bf(v1) << 16);
                ((unsigned*)out)[(size_t)v * 8 + lane] = pk;
            }
        }
    }
}

// ---------------- workspace layout (bytes) ----------------
#define O_ROWPTR   0              // 200064
#define O_DEG      200064         // 200064
#define O_BSUM     400128         // 4096
#define O_BOFF     404224         // 4096
#define O_TMPSCAN  408320         // 200064
#define O_FLAGS    608384         // 256
#define O_POS      608640         // 6,400,000
#define O_ESRC     7008640        // 6,400,000
#define O_W1HI     13408640       // 147456 (144 x 256 bf16)
#define O_W1LO     13556096       // 147456
#define O_W2HI     13703552       // 73728  (144 x 128 bf16)
#define O_W2LO     13777280       // 73728
#define O_B1F      13851008       // 512
#define O_B2F      13851520       // 512
#define O_FEATG    13852032       // 12,800,000 (fp16 [N][128], reused by both layers)
#define O_EL       26652032       // 1,600,000
#define O_ER       28252032       // 1,600,000
#define O_H        29852032       // 25,600,000 (fp32 layer-1 output)
// total ~55.5 MB

extern "C" void kernel_launch(void* const* d_in, const int* in_sizes, int n_in,
                              void* d_out, int out_size, void* d_ws, size_t ws_size,
                              hipStream_t stream) {
    const void* node_feat = d_in[0];
    const int* src = (const int*)d_in[1];
    const int* dst = (const int*)d_in[2];
    const void* W1 = d_in[3];
    const void* al1 = d_in[4];
    const void* ar1 = d_in[5];
    const void* b1 = d_in[6];
    const void* W2 = d_in[7];
    const void* al2 = d_in[8];
    const void* ar2 = d_in[9];
    const void* b2 = d_in[10];

    char* ws = (char*)d_ws;
    int* rowptr = (int*)(ws + O_ROWPTR);
    int* deg    = (int*)(ws + O_DEG);
    int* bsum   = (int*)(ws + O_BSUM);
    int* boff   = (int*)(ws + O_BOFF);
    int* tmpsc  = (int*)(ws + O_TMPSCAN);
    int* flags  = (int*)(ws + O_FLAGS);
    int* pos    = (int*)(ws + O_POS);
    int* esrc   = (int*)(ws + O_ESRC);
    ushort* w1hi = (ushort*)(ws + O_W1HI);
    ushort* w1lo = (ushort*)(ws + O_W1LO);
    ushort* w2hi = (ushort*)(ws + O_W2HI);
    ushort* w2lo = (ushort*)(ws + O_W2LO);
    float* b1f  = (float*)(ws + O_B1F);
    float* b2f  = (float*)(ws + O_B2F);
    _Float16* featg = (_Float16*)(ws + O_FEATG);
    float* el   = (float*)(ws + O_EL);
    float* er   = (float*)(ws + O_ER);
    float* hbuf = (float*)(ws + O_H);

    const int EB = (N_EDGES + 255) / 256;       // 6250
    const int GB = (3125 + 3) / 4;              // gemm blocks

    // dtype detection (must precede every flag reader)
    k_detect<<<1, 256, 0, stream>>>((const ushort*)W1, flags);

    // CSR build: one atomic pass + scan + atomic-free place
    hipMemsetAsync(ws + O_DEG, 0, N_NODES * 4, stream);
    k_count<<<EB, 256, 0, stream>>>(dst, deg, pos);
    k_scan1<<<SCAN_BLKS, 256, 0, stream>>>(deg, tmpsc, bsum);
    k_scan2<<<1, 256, 0, stream>>>(bsum, boff);
    k_scan3<<<SCAN_BLKS, 256, 0, stream>>>(tmpsc, boff, rowptr);
    k_place<<<EB, 256, 0, stream>>>(src, dst, rowptr, pos, esrc);

    // weight prep (al/ar folded in) + bias converts
    k_wprep<<<(144 * 256 + 255) / 256, 256, 0, stream>>>(W1, al1, ar1, 256, 8, w1hi, w1lo, flags);
    k_wprep<<<(144 * 128 + 255) / 256, 256, 0, stream>>>(W2, al2, ar2, 128, 7, w2hi, w2lo, flags);
    k_cvt2<<<1, 256, 0, stream>>>(b1, b2, b1f, b2f, flags);

    // layer 1
    k_gemm<<<GB, 256, 0, stream>>>(node_feat, w1hi, w1lo, featg, el, er, N_NODES, 256, flags);
    k_agg<<<(N_NODES + 3) / 4, 256, 0, stream>>>(rowptr, esrc, (const half2v*)featg, el, er, b1f, hbuf, 0, flags);

    // layer 2 (hbuf is our own fp32 buffer -> flags+1 is the constant "fp32" flag)
    k_gemm<<<GB, 256, 0, stream>>>(hbuf, w2hi, w2lo, featg, el, er, N_NODES, 128, flags + 1);
    k_agg<<<(N_NODES + 3) / 4, 256, 0, stream>>>(rowptr, esrc, (const half2v*)featg, el, er, b2f, (void*)d_out, 1, flags);
}

// Round 5
// 475.542 us; speedup vs baseline: 1.4395x; 1.1633x over previous
//
#include <hip/hip_runtime.h>
#include <hip/hip_bf16.h>

#define N_NODES 50000
#define N_EDGES 1600000
#define HEADS 8
#define HDIM 16
#define D1 128   // HEADS*HDIM
#define NEG_SLOPE 0.2f
#define SCAN_BLKS 196  // ceil(50000/256)

typedef short short8 __attribute__((ext_vector_type(8)));
typedef float f32x4 __attribute__((ext_vector_type(4)));
typedef _Float16 half2v __attribute__((ext_vector_type(2)));

// ---- dtype helpers (flag: 1 = buffers are fp32, 0 = bf16) ----
__device__ __forceinline__ float bf2f(ushort u) {
    union { unsigned u; float f; } x; x.u = ((unsigned)u) << 16; return x.f;
}
__device__ __forceinline__ ushort f2bf(float f) {
    union { float f; unsigned u; } x; x.f = f;
    unsigned r = x.u + 0x7FFF + ((x.u >> 16) & 1);   // RNE
    return (ushort)(r >> 16);
}
__device__ __forceinline__ float ldf(const void* p, size_t i, int isf32) {
    return isf32 ? ((const float*)p)[i] : bf2f(((const ushort*)p)[i]);
}

// ---------------- dtype detection ----------------
__global__ __launch_bounds__(256) void k_detect(const ushort* __restrict__ w1, int* __restrict__ flags) {
    __shared__ int sm[256];
    int t = threadIdx.x;
    int cnt = 0;
    for (int i = t; i < 32768; i += 256) {
        int e = (w1[i] >> 7) & 0xFF;
        if (e >= 0xC8) cnt++;
    }
    sm[t] = cnt; __syncthreads();
    for (int off = 128; off > 0; off >>= 1) {
        if (t < off) sm[t] += sm[t + off];
        __syncthreads();
    }
    if (t == 0) { flags[0] = (sm[0] > 0) ? 1 : 0; flags[1] = 1; }
}

// ---------------- CSR build: ONE atomic pass, 4 edges/thread ----------------
__global__ __launch_bounds__(256) void k_count(const int4* __restrict__ dst4, int* __restrict__ deg,
                                               int4* __restrict__ pos4) {
    int i = blockIdx.x * 256 + threadIdx.x;
    if (i < N_EDGES / 4) {
        int4 d = dst4[i];
        int4 p;
        p.x = atomicAdd(&deg[d.x], 1);
        p.y = atomicAdd(&deg[d.y], 1);
        p.z = atomicAdd(&deg[d.z], 1);
        p.w = atomicAdd(&deg[d.w], 1);
        pos4[i] = p;
    }
}

__global__ __launch_bounds__(256) void k_scan1(const int* __restrict__ deg, int* __restrict__ tmp, int* __restrict__ bsum) {
    __shared__ int sm[256];
    int t = threadIdx.x;
    int i = blockIdx.x * 256 + t;
    int x = (i < N_NODES) ? deg[i] : 0;
    sm[t] = x; __syncthreads();
    for (int off = 1; off < 256; off <<= 1) {
        int v = (t >= off) ? sm[t - off] : 0;
        __syncthreads();
        sm[t] += v;
        __syncthreads();
    }
    if (i < N_NODES) tmp[i] = sm[t];
    if (t == 255) bsum[blockIdx.x] = sm[255];
}

__global__ __launch_bounds__(256) void k_scan2(const int* __restrict__ bsum, int* __restrict__ boff) {
    __shared__ int sm[256];
    int t = threadIdx.x;
    int x = (t < SCAN_BLKS) ? bsum[t] : 0;
    sm[t] = x; __syncthreads();
    for (int off = 1; off < 256; off <<= 1) {
        int v = (t >= off) ? sm[t - off] : 0;
        __syncthreads();
        sm[t] += v;
        __syncthreads();
    }
    boff[t] = sm[t] - x;   // exclusive
}

__global__ __launch_bounds__(256) void k_scan3(const int* __restrict__ tmp, const int* __restrict__ boff, int* __restrict__ rowptr) {
    int i = blockIdx.x * 256 + threadIdx.x;
    if (i < N_NODES) rowptr[i + 1] = tmp[i] + boff[i >> 8];
    if (i == 0) rowptr[0] = 0;
}

// place pass: NO atomics, 4 edges/thread
__global__ __launch_bounds__(256) void k_place(const int4* __restrict__ src4, const int4* __restrict__ dst4,
                                               const int* __restrict__ rowptr, const int4* __restrict__ pos4,
                                               int* __restrict__ esrc) {
    int i = blockIdx.x * 256 + threadIdx.x;
    if (i < N_EDGES / 4) {
        int4 s = src4[i], d = dst4[i], p = pos4[i];
        esrc[rowptr[d.x] + p.x] = s.x;
        esrc[rowptr[d.y] + p.y] = s.y;
        esrc[rowptr[d.z] + p.z] = s.z;
        esrc[rowptr[d.w] + p.w] = s.w;
    }
}

// ---- extended weight prep: Bt[144][K] (bf16 hi/lo), transposed.
// rows 0..127 = W columns; 128..135 = W@al (el fold); 136..143 = W@ar.
__global__ __launch_bounds__(256) void k_wprep(const void* __restrict__ W, const void* __restrict__ al,
                                               const void* __restrict__ ar, int K, int kshift,
                                               ushort* __restrict__ whi, ushort* __restrict__ wlo,
                                               const int* __restrict__ flags) {
    int isf32 = flags[0];
    int idx = blockIdx.x * 256 + threadIdx.x;
    if (idx >= 144 * K) return;
    int n = idx >> kshift, k = idx & (K - 1);
    float f;
    if (n < 128) {
        f = ldf(W, (size_t)k * 128 + n, isf32);
    } else if (n < 136) {
        int h = n - 128;
        f = 0.f;
#pragma unroll
        for (int d = 0; d < HDIM; ++d)
            f = fmaf(ldf(W, (size_t)k * 128 + h * 16 + d, isf32), ldf(al, h * 16 + d, isf32), f);
    } else {
        int h = n - 136;
        f = 0.f;
#pragma unroll
        for (int d = 0; d < HDIM; ++d)
            f = fmaf(ldf(W, (size_t)k * 128 + h * 16 + d, isf32), ldf(ar, h * 16 + d, isf32), f);
    }
    ushort hi = f2bf(f);
    wlo[n * K + k] = f2bf(f - bf2f(hi));
    whi[n * K + k] = hi;
}

// ---------------- bias convert (both layers in one launch) ----------------
__global__ __launch_bounds__(256) void k_cvt2(const void* __restrict__ b1, const void* __restrict__ b2,
                                              float* __restrict__ o1, float* __restrict__ o2,
                                              const int* __restrict__ flags) {
    int isf32 = flags[0];
    int i = threadIdx.x;
    if (i < 128) o1[i] = ldf(b1, i, isf32);
    else o2[i - 128] = ldf(b2, i - 128, isf32);
}

// ---------------- GEMM: one wave per 16-row panel, all 9 col tiles ----------------
__global__ __launch_bounds__(256) void k_gemm(const void* __restrict__ A,
                                              const ushort* __restrict__ Bhi, const ushort* __restrict__ Blo,
                                              _Float16* __restrict__ featg,
                                              float* __restrict__ el, float* __restrict__ er,
                                              int M, int K,
                                              const int* __restrict__ flags) {
    int isf32 = flags[0];
    int wave = threadIdx.x >> 6;
    int lane = threadIdx.x & 63;
    int rt = blockIdx.x * 4 + wave;
    if (rt * 16 >= M) return;
    int quad = lane >> 4, l16 = lane & 15;
    size_t a_off = (size_t)(rt * 16 + l16) * K + quad * 8;
    const ushort* bh = Bhi + (size_t)l16 * K + quad * 8;
    const ushort* bl = Blo + (size_t)l16 * K + quad * 8;
    f32x4 acc[9];
#pragma unroll
    for (int c = 0; c < 9; ++c) acc[c] = (f32x4){0.f, 0.f, 0.f, 0.f};
    for (int kk = 0; kk < K; kk += 32) {
        float a8[8];
        if (isf32) {
            const float* ap = (const float*)A + a_off + kk;
            f32x4 u0 = *(const f32x4*)(ap);
            f32x4 u1 = *(const f32x4*)(ap + 4);
            a8[0] = u0[0]; a8[1] = u0[1]; a8[2] = u0[2]; a8[3] = u0[3];
            a8[4] = u1[0]; a8[5] = u1[1]; a8[6] = u1[2]; a8[7] = u1[3];
        } else {
            short8 s = *(const short8*)((const ushort*)A + a_off + kk);
#pragma unroll
            for (int j = 0; j < 8; ++j) a8[j] = bf2f((ushort)s[j]);
        }
        short8 ahi, alo;
#pragma unroll
        for (int j = 0; j < 8; ++j) {
            ushort h = f2bf(a8[j]);
            ahi[j] = (short)h;
            alo[j] = (short)f2bf(a8[j] - bf2f(h));
        }
#pragma unroll
        for (int c = 0; c < 9; ++c) {
            short8 bhi8 = *(const short8*)(bh + (size_t)c * 16 * K + kk);
            short8 blo8 = *(const short8*)(bl + (size_t)c * 16 * K + kk);
            acc[c] = __builtin_amdgcn_mfma_f32_16x16x32_bf16(ahi, bhi8, acc[c], 0, 0, 0);
            acc[c] = __builtin_amdgcn_mfma_f32_16x16x32_bf16(ahi, blo8, acc[c], 0, 0, 0);
            acc[c] = __builtin_amdgcn_mfma_f32_16x16x32_bf16(alo, bhi8, acc[c], 0, 0, 0);
        }
    }
    // C/D layout: col = lane&15, row = (lane>>4)*4 + reg
    int rowb = rt * 16 + quad * 4;
#pragma unroll
    for (int c = 0; c < 8; ++c) {
        int col = c * 16 + l16;
#pragma unroll
        for (int r = 0; r < 4; ++r)
            featg[(size_t)(rowb + r) * D1 + col] = (_Float16)acc[c][r];
    }
#pragma unroll
    for (int r = 0; r < 4; ++r) {
        float vv = acc[8][r];
        int row = rowb + r;
        if (l16 < 8) el[row * 8 + l16] = vv;
        else         er[row * 8 + (l16 - 8)] = vv;
    }
}

// ---------------- aggregate: one wave per dst node, batch-8 edges ----------------
// Full batches run a branch-free unrolled body: stage 8 src ids, issue all 8
// 256B gathers back-to-back (MLP), then consume. Tail handled separately.
__global__ __launch_bounds__(256) void k_agg(const int* __restrict__ rowptr, const int* __restrict__ esrc,
                                             const half2v* __restrict__ featg,
                                             const float* __restrict__ el, const float* __restrict__ er,
                                             const float* __restrict__ bias,
                                             void* __restrict__ out, int mode,
                                             const int* __restrict__ flags) {
    int wv = threadIdx.x >> 6;
    int lane = threadIdx.x & 63;
    int v = blockIdx.x * 4 + wv;
    if (v >= N_NODES) return;
    int h8 = lane & 7;            // logit head for this lane
    int esel = lane >> 3;         // logit edge-in-batch; also consumer head
    float erv = er[v * 8 + h8];
    int beg = rowptr[v], end = rowptr[v + 1];
    int deg = end - beg;
    float acc0 = 0.f, acc1 = 0.f, den = 0.f;
    int jend = beg + (deg & ~7);
    for (int j = beg; j < jend; j += 8) {
        int sv = esrc[j + h8];               // lane L: src of edge j+(L&7)
        int se = __shfl(sv, esel);
        float x = el[se * 8 + h8] + erv;     // logit(edge j+esel, head h8)
        x = x > 0.f ? x : NEG_SLOPE * x;
        float w = __expf(x);                 // lane e*8+m: weight(edge j+e, head m)
        int s_[8];
#pragma unroll
        for (int e = 0; e < 8; ++e) s_[e] = __shfl(sv, e);
        half2v hh_[8];
#pragma unroll
        for (int e = 0; e < 8; ++e) hh_[e] = featg[(size_t)s_[e] * 64 + lane];
        float we_[8];
#pragma unroll
        for (int e = 0; e < 8; ++e) we_[e] = __shfl(w, e * 8 + esel);
#pragma unroll
        for (int e = 0; e < 8; ++e) {
            den += we_[e];
            acc0 = fmaf(we_[e], (float)hh_[e][0], acc0);
            acc1 = fmaf(we_[e], (float)hh_[e][1], acc1);
        }
    }
    int rem = deg & 7;
    if (rem) {
        int idx = jend + h8;
        if (idx >= end) idx = end - 1;       // clamp (rem>0 -> end-1 >= jend)
        int sv = esrc[idx];
        int se = __shfl(sv, esel);
        float x = el[se * 8 + h8] + erv;
        x = x > 0.f ? x : NEG_SLOPE * x;
        float w = __expf(x);
        for (int e = 0; e < rem; ++e) {      // wave-uniform trip count
            float we = __shfl(w, e * 8 + esel);
            int s = __shfl(sv, e);
            half2v hh = featg[(size_t)s * 64 + lane];
            den += we;
            acc0 = fmaf(we, (float)hh[0], acc0);
            acc1 = fmaf(we, (float)hh[1], acc1);
        }
    }
    float inv = (deg > 0) ? 1.0f / den : 0.f;
    float2 bb = ((const float2*)bias)[lane];
    float r0 = fmaf(acc0, inv, bb.x);
    float r1 = fmaf(acc1, inv, bb.y);
    if (mode == 0) {
        r0 = r0 > 0.f ? r0 : (__expf(r0) - 1.f);   // ELU
        r1 = r1 > 0.f ? r1 : (__expf(r1) - 1.f);
        float2 st = {r0, r1};
        ((float2*)out)[(size_t)v * 64 + lane] = st;
    } else {
        // mean over heads: lanes i, i^8, i^16, i^32 hold same channels of different heads
        for (int m = 8; m < 64; m <<= 1) {
            r0 += __shfl_xor(r0, m);
            r1 += __shfl_xor(r1, m);
        }
        if (lane < 8) {
            float v0 = r0 * 0.125f, v1 = r1 * 0.125f;
            if (flags[0]) {
                float2 st = {v0, v1};
                ((float2*)out)[(size_t)v * 8 + lane] = st;
            } else {
                unsigned pk = (unsigned)f2bf(v0) | ((unsigned)f2bf(v1) << 16);
                ((unsigned*)out)[(size_t)v * 8 + lane] = pk;
            }
        }
    }
}

// ---------------- workspace layout (bytes) ----------------
#define O_ROWPTR   0              // 200064
#define O_DEG      200064         // 200064
#define O_BSUM     400128         // 4096
#define O_BOFF     404224         // 4096
#define O_TMPSCAN  408320         // 200064
#define O_FLAGS    608384         // 256
#define O_POS      608640         // 6,400,000
#define O_ESRC     7008640        // 6,400,000
#define O_W1HI     13408640       // 147456 (144 x 256 bf16)
#define O_W1LO     13556096       // 147456
#define O_W2HI     13703552       // 73728  (144 x 128 bf16)
#define O_W2LO     13777280       // 73728
#define O_B1F      13851008       // 512
#define O_B2F      13851520       // 512
#define O_FEATG    13852032       // 12,800,000 (fp16 [N][128], reused by both layers)
#define O_EL       26652032       // 1,600,000
#define O_ER       28252032       // 1,600,000
#define O_H        29852032       // 25,600,000 (fp32 layer-1 output)
// total ~55.5 MB

extern "C" void kernel_launch(void* const* d_in, const int* in_sizes, int n_in,
                              void* d_out, int out_size, void* d_ws, size_t ws_size,
                              hipStream_t stream) {
    const void* node_feat = d_in[0];
    const int* src = (const int*)d_in[1];
    const int* dst = (const int*)d_in[2];
    const void* W1 = d_in[3];
    const void* al1 = d_in[4];
    const void* ar1 = d_in[5];
    const void* b1 = d_in[6];
    const void* W2 = d_in[7];
    const void* al2 = d_in[8];
    const void* ar2 = d_in[9];
    const void* b2 = d_in[10];

    char* ws = (char*)d_ws;
    int* rowptr = (int*)(ws + O_ROWPTR);
    int* deg    = (int*)(ws + O_DEG);
    int* bsum   = (int*)(ws + O_BSUM);
    int* boff   = (int*)(ws + O_BOFF);
    int* tmpsc  = (int*)(ws + O_TMPSCAN);
    int* flags  = (int*)(ws + O_FLAGS);
    int* pos    = (int*)(ws + O_POS);
    int* esrc   = (int*)(ws + O_ESRC);
    ushort* w1hi = (ushort*)(ws + O_W1HI);
    ushort* w1lo = (ushort*)(ws + O_W1LO);
    ushort* w2hi = (ushort*)(ws + O_W2HI);
    ushort* w2lo = (ushort*)(ws + O_W2LO);
    float* b1f  = (float*)(ws + O_B1F);
    float* b2f  = (float*)(ws + O_B2F);
    _Float16* featg = (_Float16*)(ws + O_FEATG);
    float* el   = (float*)(ws + O_EL);
    float* er   = (float*)(ws + O_ER);
    float* hbuf = (float*)(ws + O_H);

    const int EB4 = (N_EDGES / 4 + 255) / 256;  // 1563
    const int GB = (3125 + 3) / 4;              // gemm blocks

    // dtype detection (must precede every flag reader)
    k_detect<<<1, 256, 0, stream>>>((const ushort*)W1, flags);

    // CSR build: one atomic pass + scan + atomic-free place
    hipMemsetAsync(ws + O_DEG, 0, N_NODES * 4, stream);
    k_count<<<EB4, 256, 0, stream>>>((const int4*)dst, deg, (int4*)pos);
    k_scan1<<<SCAN_BLKS, 256, 0, stream>>>(deg, tmpsc, bsum);
    k_scan2<<<1, 256, 0, stream>>>(bsum, boff);
    k_scan3<<<SCAN_BLKS, 256, 0, stream>>>(tmpsc, boff, rowptr);
    k_place<<<EB4, 256, 0, stream>>>((const int4*)src, (const int4*)dst, rowptr, (const int4*)pos, esrc);

    // weight prep (al/ar folded in) + bias converts
    k_wprep<<<(144 * 256 + 255) / 256, 256, 0, stream>>>(W1, al1, ar1, 256, 8, w1hi, w1lo, flags);
    k_wprep<<<(144 * 128 + 255) / 256, 256, 0, stream>>>(W2, al2, ar2, 128, 7, w2hi, w2lo, flags);
    k_cvt2<<<1, 256, 0, stream>>>(b1, b2, b1f, b2f, flags);

    // layer 1
    k_gemm<<<GB, 256, 0, stream>>>(node_feat, w1hi, w1lo, featg, el, er, N_NODES, 256, flags);
    k_agg<<<(N_NODES + 3) / 4, 256, 0, stream>>>(rowptr, esrc, (const half2v*)featg, el, er, b1f, hbuf, 0, flags);

    // layer 2 (hbuf is our own fp32 buffer -> flags+1 is the constant "fp32" flag)
    k_gemm<<<GB, 256, 0, stream>>>(hbuf, w2hi, w2lo, featg, el, er, N_NODES, 128, flags + 1);
    k_agg<<<(N_NODES + 3) / 4, 256, 0, stream>>>(rowptr, esrc, (const half2v*)featg, el, er, b2f, (void*)d_out, 1, flags);
}